// Round 8
// baseline (2761.162 us; speedup 1.0000x reference)
//
#include <hip/hip_runtime.h>

typedef __bf16 bf16_t;
typedef __bf16 bf16x8 __attribute__((ext_vector_type(8)));
typedef __bf16 bf16x4 __attribute__((ext_vector_type(4)));
typedef __bf16 bf16x2 __attribute__((ext_vector_type(2)));
typedef float f32x16 __attribute__((ext_vector_type(16)));
typedef int i32x4 __attribute__((ext_vector_type(4)));

// Problem dims: B=32, S=512, D=512, H=1024, 4H=4096
// ws layout (bytes)
#define SZ_XBF    (16384ull*512*2)      // x bf16, rows permuted to t*32+b
#define SZ_WIH    (4096ull*512*2)
#define SZ_WHH    (4096ull*1024*2)
#define SZ_XPROJ  (16384ull*4096*2)     // [t*32+b][4096] bf16
#define SZ_HTR    (513ull*32*1024*2)    // h trace bf16, slot 0 = h0
#define SZ_RDY    (33024ull*4)          // ready vector: rdy[t*64 + wg]
#define OFF_XBF   (0ull)
#define OFF_WIH   (OFF_XBF + SZ_XBF)
#define OFF_WHH   (OFF_WIH + SZ_WIH)
#define OFF_XPROJ (OFF_WHH + SZ_WHH)
#define OFF_HTR   (OFF_XPROJ + SZ_XPROJ)
#define OFF_RDY   (OFF_HTR + SZ_HTR)

// h trace layout (slab-contiguous per producer, round-4 topology):
//   HTR[t*32768 + slab*512 + b*16 + col]  encodes h_t[b][slab*16 + col]
// slab = 1KB (slab index == producer wg). Slots 1..512 pre-filled with canary
// 0xFFFFFFFF (bf16 -NaN pair, impossible for finite h).
// Round 8 protocol (3 layers):
//  1. HINT: producer stores rdy[t+1][wg]=1 (sc1, fire-and-forget) after a
//     publish-side __syncthreads (all 256 h-stores issued first). Consumers
//     spin on ONE 256B wave-load covering all 64 producers.
//  2. PLAIN CACHED BULK: after the hint, slabs are read with normal cached
//     loads -> 8 WGs per XCD share the lines via L2 (~8x less LLC read
//     traffic, L2-hit latency for 7/8 WGs). Safe only because nothing reads
//     the slab before the hint (no stale-canary L2 lines in the common case).
//  3. CANARY VALIDATION (ground truth, unchanged) + sc0sc1 retry fallback
//     for the rare hint-before-data store-skew race. Correctness never
//     rests on the hint.

// ---------------------------------------------------------------------------
// Kernel 1: convert inputs to bf16 (x permuted), init h-trace slot 0,
//           canary-fill h-trace slots 1..512, zero ready vector
// ---------------------------------------------------------------------------
__global__ __launch_bounds__(256) void convert_pack(
    const float* __restrict__ x, const float* __restrict__ h0,
    const float* __restrict__ Wih, const float* __restrict__ Whh,
    bf16_t* __restrict__ xbf, bf16_t* __restrict__ wihbf,
    bf16_t* __restrict__ whhbf, bf16_t* __restrict__ htr,
    int* __restrict__ rdy)
{
  long long v = (long long)blockIdx.x * 256 + threadIdx.x;
  if (v < 2097152LL) {                       // x: 8388608 floats, 4 per thread
    long long fi = v * 4;
    int b = (int)(fi >> 18);                 // 512*512 = 2^18
    int rem = (int)(fi & 0x3FFFF);
    int s = rem >> 9, d = rem & 511;
    float4 f = *(const float4*)(x + fi);
    bf16x4 o; o.x = (bf16_t)f.x; o.y = (bf16_t)f.y; o.z = (bf16_t)f.z; o.w = (bf16_t)f.w;
    *(bf16x4*)(xbf + ((long long)(s*32 + b)*512 + d)) = o;
  } else if (v < 2621440LL) {                // W_ih: 2097152 floats
    long long fi = (v - 2097152LL) * 4;
    float4 f = *(const float4*)(Wih + fi);
    bf16x4 o; o.x = (bf16_t)f.x; o.y = (bf16_t)f.y; o.z = (bf16_t)f.z; o.w = (bf16_t)f.w;
    *(bf16x4*)(wihbf + fi) = o;
  } else if (v < 3670016LL) {                // W_hh: 4194304 floats
    long long fi = (v - 2621440LL) * 4;
    float4 f = *(const float4*)(Whh + fi);
    bf16x4 o; o.x = (bf16_t)f.x; o.y = (bf16_t)f.y; o.z = (bf16_t)f.z; o.w = (bf16_t)f.w;
    *(bf16x4*)(whhbf + fi) = o;
  } else if (v < 3678208LL) {                // h0: 32768 floats -> htr slot 0 (slab layout)
    long long fi = (v - 3670016LL) * 4;
    int b = (int)(fi >> 10), c = (int)(fi & 1023);
    float4 f = *(const float4*)(h0 + fi);
    bf16x4 o; o.x = (bf16_t)f.x; o.y = (bf16_t)f.y; o.z = (bf16_t)f.z; o.w = (bf16_t)f.w;
    *(bf16x4*)(htr + (long long)(c >> 4) * 512 + b * 16 + (c & 15)) = o;
  } else if (v < 5775360LL) {                // canary fill slots 1..512 (16.78M elems)
    long long idx = v - 3678208LL;           // 2097152 threads * 8 elems
    *(int4*)(htr + 32768LL + idx * 8) = make_int4(-1, -1, -1, -1);
  } else if (v < 5783616LL) {                // zero ready vector (33024 dwords)
    long long idx = v - 5775360LL;           // 8256 threads * 4 dwords
    *(int4*)(rdy + idx * 4) = make_int4(0, 0, 0, 0);
  }
}

// ---------------------------------------------------------------------------
// Kernel 2: x_proj = X(bf16, rows t*32+b) @ W_ih^T + b_ih + b_hh  -> bf16
// ---------------------------------------------------------------------------
__global__ __launch_bounds__(256) void xproj_gemm(
    const bf16_t* __restrict__ Xb, const bf16_t* __restrict__ Wb,
    const float* __restrict__ bih, const float* __restrict__ bhh,
    bf16_t* __restrict__ XP)
{
  __shared__ bf16_t As[128*64];
  __shared__ bf16_t Bs[128*64];
  const int tid = threadIdx.x;
  const int lane = tid & 63, wave = tid >> 6;
  const int mhalf = wave & 1, nhalf = wave >> 1;
  const int l31 = lane & 31, khi = lane >> 5;
  const int m0 = blockIdx.x * 128, n0 = blockIdx.y * 128;

  f32x16 acc[2][2] = {};

  for (int kb = 0; kb < 8; ++kb) {
    const int k0 = kb * 64;
    __syncthreads();
#pragma unroll
    for (int j = 0; j < 4; ++j) {
      int cid = j * 256 + tid;
      int r = cid >> 3, bs = cid & 7;
      int bb = bs ^ (r & 7);
      *(bf16x8*)(As + cid * 8) = *(const bf16x8*)(Xb + (long long)(m0 + r) * 512 + k0 + bb * 8);
      *(bf16x8*)(Bs + cid * 8) = *(const bf16x8*)(Wb + (long long)(n0 + r) * 512 + k0 + bb * 8);
    }
    __syncthreads();
#pragma unroll
    for (int ks = 0; ks < 4; ++ks) {
      int blk = ks * 2 + khi;
      bf16x8 af[2], bfr[2];
#pragma unroll
      for (int mt = 0; mt < 2; ++mt) {
        int r = mhalf * 64 + mt * 32 + l31;
        af[mt] = *(const bf16x8*)(As + (r * 8 + (blk ^ (r & 7))) * 8);
      }
#pragma unroll
      for (int nt = 0; nt < 2; ++nt) {
        int r = nhalf * 64 + nt * 32 + l31;
        bfr[nt] = *(const bf16x8*)(Bs + (r * 8 + (blk ^ (r & 7))) * 8);
      }
#pragma unroll
      for (int mt = 0; mt < 2; ++mt)
#pragma unroll
        for (int nt = 0; nt < 2; ++nt)
          acc[mt][nt] = __builtin_amdgcn_mfma_f32_32x32x16_bf16(af[mt], bfr[nt], acc[mt][nt], 0, 0, 0);
    }
  }
#pragma unroll
  for (int nt = 0; nt < 2; ++nt) {
    int ng = n0 + nhalf * 64 + nt * 32 + l31;
    float bias = bih[ng] + bhh[ng];
#pragma unroll
    for (int mt = 0; mt < 2; ++mt) {
#pragma unroll
      for (int r = 0; r < 16; ++r) {
        int row = (r & 3) + 8 * (r >> 2) + 4 * khi;
        long long mg = m0 + mhalf * 64 + mt * 32 + row;   // = t*32 + b
        XP[mg * 4096 + ng] = (bf16_t)(acc[mt][nt][r] + bias);
      }
    }
  }
}

// ---------------------------------------------------------------------------
// Kernel 3: persistent LSTM recurrence, hint + cached-bulk + canary-validate.
// 64 WGs x 256 threads (round-4 topology); WG owns 16 h-cols (64 gate rows).
//  - wave = K-quarter: 16 disjoint slabs (16KB), computes BOTH n-tiles.
//  - ready-vector probe: ONE 256B wave-load covers all 64 producers.
//  - bulk loads PLAIN (L1/L2-cached): 8 WGs/XCD share lines via L2.
//  - canary validation + sc0sc1 retry fallback = ground-truth correctness.
//  - gL [parity][4 kq][32 m][65] double-buffered; barrier A after gL writes,
//    barrier B after publish (orders h-store issue before ready store).
// ---------------------------------------------------------------------------
__device__ __forceinline__ float sigf(float x) { return 1.0f / (1.0f + __expf(-x)); }
__device__ __forceinline__ float tanhfast(float x) {
  float e = __expf(-2.0f * fabsf(x));
  float t = (1.0f - e) / (1.0f + e);
  return copysignf(t, x);
}
__device__ __forceinline__ unsigned umax2(unsigned a, unsigned b) { return a > b ? a : b; }
__device__ __forceinline__ unsigned umax4(i32x4 v) {
  return umax2(umax2((unsigned)v[0], (unsigned)v[1]),
               umax2((unsigned)v[2], (unsigned)v[3]));
}

#define LD16(dst, ptr, OFF) \
  asm volatile("global_load_dwordx4 %0, %1, off offset:" OFF " sc0 sc1" \
               : "=v"(dst) : "v"(ptr) : "memory")

__global__ __launch_bounds__(256, 1) void lstm_rec(
    const bf16_t* __restrict__ Whh_b, const bf16_t* __restrict__ XP,
    const float* __restrict__ c0, float* __restrict__ OUT,
    bf16_t* __restrict__ HTR, int* RDY)
{
  const int tid = threadIdx.x;
  const int lane = tid & 63, wave = tid >> 6;
  const int kq = wave;                              // K-quarter 0..3
  const int wg = blockIdx.x;
  const int l31 = lane & 31, khi = lane >> 5;

  // --- preload W_hh fragments for BOTH n-tiles of my K-quarter ---
  const int g0row = (l31 >> 4) * 1024 + wg * 16 + (l31 & 15);
  const int g1row = (2 + (l31 >> 4)) * 1024 + wg * 16 + (l31 & 15);
  const int kqb = kq * 256 + khi * 8;               // k-base of my quarter
  bf16x8 w0[16], w1[16];
#pragma unroll
  for (int s = 0; s < 16; ++s) {
    w0[s] = *(const bf16x8*)(Whh_b + (long long)g0row * 1024 + kqb + s * 16);
    w1[s] = *(const bf16x8*)(Whh_b + (long long)g1row * 1024 + kqb + s * 16);
  }

  // A-fragment byte base: slab (kq*16+s), row l31, cols khi*8..+8
  const char* abase = (const char*)HTR + kq * 16384 + l31 * 32 + khi * 16;
  // ready probe: lane l covers producer l
  const char* rbase = (const char*)RDY + lane * 4;

  __shared__ float gLb[2][4][32][65];   // [t parity][kq][m][n_local], padded
  const int m_e = tid >> 3;
  const int jp = (tid & 7) * 2;
  float cr0 = c0[m_e * 1024 + wg * 16 + jp];
  float cr1 = c0[m_e * 1024 + wg * 16 + jp + 1];

  // prefetch xp for t=0
  float xp[4][2];
  {
    const bf16_t* xpb = XP + (long long)m_e * 4096 + wg * 16 + jp;
#pragma unroll
    for (int g = 0; g < 4; ++g) {
      bf16x2 v = *(const bf16x2*)(xpb + g * 1024);
      xp[g][0] = (float)v.x; xp[g][1] = (float)v.y;
    }
  }

  float po0 = 0.0f, po1 = 0.0f;   // deferred OUT values (step t-1)

  for (int t = 0; t < 512; ++t) {
    // ---- ready-vector probe: one 256B wave-load covers all 64 producers ----
    if (t) {
      const char* rp = rbase + ((long long)t << 8);
      unsigned rv;
      for (;;) {
        asm volatile("global_load_dword %0, %1, off sc0 sc1"
                     : "=v"(rv) : "v"(rp) : "memory");
        asm volatile("s_waitcnt vmcnt(0)" ::: "memory");
        if (__all((int)(rv != 0u))) break;
      }
    }

    // ---- PLAIN cached bulk load of my 16 slabs (L2-shared across XCD) ----
    const char* pb = abase + ((long long)t << 16);
    i32x4 a[16];
#pragma unroll
    for (int s = 0; s < 16; ++s)
      a[s] = *(const i32x4*)(pb + s * 1024);

    // ---- canary validation (ground truth); sc0sc1 retry fallback ----
    {
      unsigned mA = 0, mB = 0, mC = 0, mD = 0;
#pragma unroll
      for (int s = 0; s < 16; s += 4) {
        mA = umax2(mA, umax4(a[s]));
        mB = umax2(mB, umax4(a[s + 1]));
        mC = umax2(mC, umax4(a[s + 2]));
        mD = umax2(mD, umax4(a[s + 3]));
      }
      unsigned mx = umax2(umax2(mA, mB), umax2(mC, mD));
      if (__any((int)(mx == 0xFFFFFFFFu))) {
        const char* p0 = pb;
        const char* p1 = pb + 4096;
        const char* p2 = pb + 8192;
        const char* p3 = pb + 12288;
        for (;;) {
          LD16(a[0],  p0, "0"); LD16(a[1],  p0, "1024"); LD16(a[2],  p0, "2048"); LD16(a[3],  p0, "3072");
          LD16(a[4],  p1, "0"); LD16(a[5],  p1, "1024"); LD16(a[6],  p1, "2048"); LD16(a[7],  p1, "3072");
          LD16(a[8],  p2, "0"); LD16(a[9],  p2, "1024"); LD16(a[10], p2, "2048"); LD16(a[11], p2, "3072");
          LD16(a[12], p3, "0"); LD16(a[13], p3, "1024"); LD16(a[14], p3, "2048"); LD16(a[15], p3, "3072");
          asm volatile("s_waitcnt vmcnt(0)" ::: "memory");
          __builtin_amdgcn_sched_barrier(0);
          unsigned nA = 0, nB = 0, nC = 0, nD = 0;
#pragma unroll
          for (int s = 0; s < 16; s += 4) {
            nA = umax2(nA, umax4(a[s]));
            nB = umax2(nB, umax4(a[s + 1]));
            nC = umax2(nC, umax4(a[s + 2]));
            nD = umax2(nD, umax4(a[s + 3]));
          }
          unsigned nx = umax2(umax2(nA, nB), umax2(nC, nD));
          if (!__any((int)(nx == 0xFFFFFFFFu))) break;
        }
      }
    }

    // ---- deferred OUT store for step t-1 (ack off the critical wait) ----
    if (t > 0)
      *(float2*)(OUT + ((long long)m_e * 512 + (t - 1)) * 1024 + wg * 16 + jp) =
          make_float2(po0, po1);

    // ---- gates partial for my K-quarter, both n-tiles ----
    f32x16 acc0 = {}, acc1 = {};
#pragma unroll
    for (int s = 0; s < 16; ++s) {
      bf16x8 af = __builtin_bit_cast(bf16x8, a[s]);
      acc0 = __builtin_amdgcn_mfma_f32_32x32x16_bf16(af, w0[s], acc0, 0, 0, 0);
      acc1 = __builtin_amdgcn_mfma_f32_32x32x16_bf16(af, w1[s], acc1, 0, 0, 0);
    }

    float (*gp)[65] = gLb[t & 1][kq];
#pragma unroll
    for (int r = 0; r < 16; ++r) {
      int mm = (r & 3) + 8 * (r >> 2) + 4 * khi;
      gp[mm][l31]      = acc0[r];
      gp[mm][32 + l31] = acc1[r];
    }
    __syncthreads();   // barrier A: all partials in gL

    // ---- elementwise LSTM cell for (m_e, jp..jp+1), c in registers ----
    float (*ge)[32][65] = gLb[t & 1];
    float hv[2];
    {
      float ir  = ge[0][m_e][jp]      + ge[1][m_e][jp]      + ge[2][m_e][jp]      + ge[3][m_e][jp]      + xp[0][0];
      float fr  = ge[0][m_e][16 + jp] + ge[1][m_e][16 + jp] + ge[2][m_e][16 + jp] + ge[3][m_e][16 + jp] + xp[1][0];
      float gr  = ge[0][m_e][32 + jp] + ge[1][m_e][32 + jp] + ge[2][m_e][32 + jp] + ge[3][m_e][32 + jp] + xp[2][0];
      float orr = ge[0][m_e][48 + jp] + ge[1][m_e][48 + jp] + ge[2][m_e][48 + jp] + ge[3][m_e][48 + jp] + xp[3][0];
      float c = sigf(fr) * cr0 + sigf(ir) * tanhfast(gr);
      cr0 = c;
      hv[0] = sigf(orr) * tanhfast(c);
    }
    {
      int j = jp + 1;
      float ir  = ge[0][m_e][j]      + ge[1][m_e][j]      + ge[2][m_e][j]      + ge[3][m_e][j]      + xp[0][1];
      float fr  = ge[0][m_e][16 + j] + ge[1][m_e][16 + j] + ge[2][m_e][16 + j] + ge[3][m_e][16 + j] + xp[1][1];
      float gr  = ge[0][m_e][32 + j] + ge[1][m_e][32 + j] + ge[2][m_e][32 + j] + ge[3][m_e][32 + j] + xp[2][1];
      float orr = ge[0][m_e][48 + j] + ge[1][m_e][48 + j] + ge[2][m_e][48 + j] + ge[3][m_e][48 + j] + xp[3][1];
      float c = sigf(fr) * cr1 + sigf(ir) * tanhfast(gr);
      cr1 = c;
      hv[1] = sigf(orr) * tanhfast(c);
    }

    // ---- publish h: sc1 store to LLC, fire-and-forget (canary = flag) ----
    {
      bf16x2 h2; h2.x = (bf16_t)hv[0]; h2.y = (bf16_t)hv[1];
      unsigned int u = __builtin_bit_cast(unsigned int, h2);
      unsigned int* dst = (unsigned int*)(HTR + (long long)(t + 1) * 32768 +
                                          (long long)wg * 512 + m_e * 16 + jp);
      __hip_atomic_store(dst, u, __ATOMIC_RELAXED, __HIP_MEMORY_SCOPE_AGENT);
    }
    po0 = hv[0]; po1 = hv[1];

    // ---- next-step xp prefetch (loads in flight across barrier B) ----
    if (t < 511) {
      const bf16_t* xpb = XP + ((long long)(t + 1) * 32 + m_e) * 4096 + wg * 16 + jp;
#pragma unroll
      for (int g = 0; g < 4; ++g) {
        bf16x2 v = *(const bf16x2*)(xpb + g * 1024);
        xp[g][0] = (float)v.x; xp[g][1] = (float)v.y;
      }
    }

    __syncthreads();   // barrier B: all h stores ISSUED before ready hint
    if (tid == 0 && t < 511)
      __hip_atomic_store(&RDY[(t + 1) * 64 + wg], 1, __ATOMIC_RELAXED,
                         __HIP_MEMORY_SCOPE_AGENT);
  }
  // final OUT store (t = 511)
  *(float2*)(OUT + ((long long)m_e * 512 + 511) * 1024 + wg * 16 + jp) =
      make_float2(po0, po1);
}

// ---------------------------------------------------------------------------
extern "C" void kernel_launch(void* const* d_in, const int* in_sizes, int n_in,
                              void* d_out, int out_size, void* d_ws, size_t ws_size,
                              hipStream_t stream)
{
  const float* x   = (const float*)d_in[0];
  const float* h0  = (const float*)d_in[1];
  const float* c0  = (const float*)d_in[2];
  const float* Wih = (const float*)d_in[3];
  const float* Whh = (const float*)d_in[4];
  const float* bih = (const float*)d_in[5];
  const float* bhh = (const float*)d_in[6];
  float* out = (float*)d_out;

  char* ws = (char*)d_ws;
  bf16_t* xbf   = (bf16_t*)(ws + OFF_XBF);
  bf16_t* wihbf = (bf16_t*)(ws + OFF_WIH);
  bf16_t* whhbf = (bf16_t*)(ws + OFF_WHH);
  bf16_t* xproj = (bf16_t*)(ws + OFF_XPROJ);
  bf16_t* htr   = (bf16_t*)(ws + OFF_HTR);
  int* rdy      = (int*)(ws + OFF_RDY);

  convert_pack<<<22593, 256, 0, stream>>>(x, h0, Wih, Whh, xbf, wihbf, whhbf, htr, rdy);
  xproj_gemm<<<dim3(128, 32), 256, 0, stream>>>(xbf, wihbf, bih, bhh, xproj);
  lstm_rec<<<64, 256, 0, stream>>>(whhbf, xproj, c0, out, htr, rdy);
}

// Round 9
// 1776.561 us; speedup vs baseline: 1.5542x; 1.5542x over previous
//
#include <hip/hip_runtime.h>

typedef __bf16 bf16_t;
typedef __bf16 bf16x8 __attribute__((ext_vector_type(8)));
typedef __bf16 bf16x4 __attribute__((ext_vector_type(4)));
typedef __bf16 bf16x2 __attribute__((ext_vector_type(2)));
typedef float f32x16 __attribute__((ext_vector_type(16)));
typedef int i32x4 __attribute__((ext_vector_type(4)));

// Problem dims: B=32, S=512, D=512, H=1024, 4H=4096
// ws layout (bytes)
#define SZ_XBF    (16384ull*512*2)      // x bf16, rows permuted to t*32+b
#define SZ_WIH    (4096ull*512*2)
#define SZ_WHH    (4096ull*1024*2)
#define SZ_XPROJ  (16384ull*4096*2)     // [t*32+b][4096] bf16
#define SZ_HTR    (513ull*32*1024*2)    // h trace bf16, slot 0 = h0
#define OFF_XBF   (0ull)
#define OFF_WIH   (OFF_XBF + SZ_XBF)
#define OFF_WHH   (OFF_WIH + SZ_WIH)
#define OFF_XPROJ (OFF_WHH + SZ_WHH)
#define OFF_HTR   (OFF_XPROJ + SZ_XPROJ)

// h trace layout (slab-contiguous per producer, round-4 topology):
//   HTR[t*32768 + slab*512 + b*16 + col]  encodes h_t[b][slab*16 + col]
// slab = 1KB, written dword-wise by exactly one WG. Slots 1..512 pre-filled
// with canary 0xFFFFFFFF (bf16 -NaN pair, impossible for finite h).
// Consumers bulk-load with cache-bypassing loads; data IS the flag.
// Round 9: A/B DOUBLE-BUFFERED poll rounds. Two 16-load rounds in flight;
// counted vmcnt(16) drains the older while the newer flies; validate ->
// reissue only the failed buffer. Detect quantization ~halves vs r4's
// serial round. Register hazard: the loser's stale round is drained at the
// NEXT step via vmcnt(10) (leaves exactly publish+xp8+OUT outstanding ->
// publish stays fire-and-forget).

// ---------------------------------------------------------------------------
// Kernel 1: convert inputs to bf16 (x permuted), init h-trace slot 0,
//           canary-fill h-trace slots 1..512
// ---------------------------------------------------------------------------
__global__ __launch_bounds__(256) void convert_pack(
    const float* __restrict__ x, const float* __restrict__ h0,
    const float* __restrict__ Wih, const float* __restrict__ Whh,
    bf16_t* __restrict__ xbf, bf16_t* __restrict__ wihbf,
    bf16_t* __restrict__ whhbf, bf16_t* __restrict__ htr)
{
  long long v = (long long)blockIdx.x * 256 + threadIdx.x;
  if (v < 2097152LL) {                       // x: 8388608 floats, 4 per thread
    long long fi = v * 4;
    int b = (int)(fi >> 18);                 // 512*512 = 2^18
    int rem = (int)(fi & 0x3FFFF);
    int s = rem >> 9, d = rem & 511;
    float4 f = *(const float4*)(x + fi);
    bf16x4 o; o.x = (bf16_t)f.x; o.y = (bf16_t)f.y; o.z = (bf16_t)f.z; o.w = (bf16_t)f.w;
    *(bf16x4*)(xbf + ((long long)(s*32 + b)*512 + d)) = o;
  } else if (v < 2621440LL) {                // W_ih: 2097152 floats
    long long fi = (v - 2097152LL) * 4;
    float4 f = *(const float4*)(Wih + fi);
    bf16x4 o; o.x = (bf16_t)f.x; o.y = (bf16_t)f.y; o.z = (bf16_t)f.z; o.w = (bf16_t)f.w;
    *(bf16x4*)(wihbf + fi) = o;
  } else if (v < 3670016LL) {                // W_hh: 4194304 floats
    long long fi = (v - 2621440LL) * 4;
    float4 f = *(const float4*)(Whh + fi);
    bf16x4 o; o.x = (bf16_t)f.x; o.y = (bf16_t)f.y; o.z = (bf16_t)f.z; o.w = (bf16_t)f.w;
    *(bf16x4*)(whhbf + fi) = o;
  } else if (v < 3678208LL) {                // h0: 32768 floats -> htr slot 0 (slab layout)
    long long fi = (v - 3670016LL) * 4;
    int b = (int)(fi >> 10), c = (int)(fi & 1023);
    float4 f = *(const float4*)(h0 + fi);
    bf16x4 o; o.x = (bf16_t)f.x; o.y = (bf16_t)f.y; o.z = (bf16_t)f.z; o.w = (bf16_t)f.w;
    *(bf16x4*)(htr + (long long)(c >> 4) * 512 + b * 16 + (c & 15)) = o;
  } else if (v < 5775360LL) {                // canary fill slots 1..512 (16.78M elems)
    long long idx = v - 3678208LL;           // 2097152 threads * 8 elems
    *(int4*)(htr + 32768LL + idx * 8) = make_int4(-1, -1, -1, -1);
  }
}

// ---------------------------------------------------------------------------
// Kernel 2: x_proj = X(bf16, rows t*32+b) @ W_ih^T + b_ih + b_hh  -> bf16
// ---------------------------------------------------------------------------
__global__ __launch_bounds__(256) void xproj_gemm(
    const bf16_t* __restrict__ Xb, const bf16_t* __restrict__ Wb,
    const float* __restrict__ bih, const float* __restrict__ bhh,
    bf16_t* __restrict__ XP)
{
  __shared__ bf16_t As[128*64];
  __shared__ bf16_t Bs[128*64];
  const int tid = threadIdx.x;
  const int lane = tid & 63, wave = tid >> 6;
  const int mhalf = wave & 1, nhalf = wave >> 1;
  const int l31 = lane & 31, khi = lane >> 5;
  const int m0 = blockIdx.x * 128, n0 = blockIdx.y * 128;

  f32x16 acc[2][2] = {};

  for (int kb = 0; kb < 8; ++kb) {
    const int k0 = kb * 64;
    __syncthreads();
#pragma unroll
    for (int j = 0; j < 4; ++j) {
      int cid = j * 256 + tid;
      int r = cid >> 3, bs = cid & 7;
      int bb = bs ^ (r & 7);
      *(bf16x8*)(As + cid * 8) = *(const bf16x8*)(Xb + (long long)(m0 + r) * 512 + k0 + bb * 8);
      *(bf16x8*)(Bs + cid * 8) = *(const bf16x8*)(Wb + (long long)(n0 + r) * 512 + k0 + bb * 8);
    }
    __syncthreads();
#pragma unroll
    for (int ks = 0; ks < 4; ++ks) {
      int blk = ks * 2 + khi;
      bf16x8 af[2], bfr[2];
#pragma unroll
      for (int mt = 0; mt < 2; ++mt) {
        int r = mhalf * 64 + mt * 32 + l31;
        af[mt] = *(const bf16x8*)(As + (r * 8 + (blk ^ (r & 7))) * 8);
      }
#pragma unroll
      for (int nt = 0; nt < 2; ++nt) {
        int r = nhalf * 64 + nt * 32 + l31;
        bfr[nt] = *(const bf16x8*)(Bs + (r * 8 + (blk ^ (r & 7))) * 8);
      }
#pragma unroll
      for (int mt = 0; mt < 2; ++mt)
#pragma unroll
        for (int nt = 0; nt < 2; ++nt)
          acc[mt][nt] = __builtin_amdgcn_mfma_f32_32x32x16_bf16(af[mt], bfr[nt], acc[mt][nt], 0, 0, 0);
    }
  }
#pragma unroll
  for (int nt = 0; nt < 2; ++nt) {
    int ng = n0 + nhalf * 64 + nt * 32 + l31;
    float bias = bih[ng] + bhh[ng];
#pragma unroll
    for (int mt = 0; mt < 2; ++mt) {
#pragma unroll
      for (int r = 0; r < 16; ++r) {
        int row = (r & 3) + 8 * (r >> 2) + 4 * khi;
        long long mg = m0 + mhalf * 64 + mt * 32 + row;   // = t*32 + b
        XP[mg * 4096 + ng] = (bf16_t)(acc[mt][nt][r] + bias);
      }
    }
  }
}

// ---------------------------------------------------------------------------
// Kernel 3: persistent LSTM recurrence, canary-validated data-poll sync.
// 64 WGs x 256 threads (r4 topology); WG owns 16 h-cols (64 gate rows).
//  - wave = K-quarter: 16 disjoint slabs (16KB), computes BOTH n-tiles.
//  - A/B double-buffered poll rounds (see header comment).
//  - gL [parity][4 kq][32 m][65] double-buffered -> one barrier per step.
//  - c in regs; OUT deferred one step and issued BEFORE the poll (hidden).
// ---------------------------------------------------------------------------
__device__ __forceinline__ float sigf(float x) { return 1.0f / (1.0f + __expf(-x)); }
__device__ __forceinline__ float tanhfast(float x) {
  float e = __expf(-2.0f * fabsf(x));
  float t = (1.0f - e) / (1.0f + e);
  return copysignf(t, x);
}
__device__ __forceinline__ unsigned umax2(unsigned a, unsigned b) { return a > b ? a : b; }
__device__ __forceinline__ unsigned umax4(i32x4 v) {
  return umax2(umax2((unsigned)v[0], (unsigned)v[1]),
               umax2((unsigned)v[2], (unsigned)v[3]));
}

#define LD16(dst, ptr, OFF) \
  asm volatile("global_load_dwordx4 %0, %1, off offset:" OFF " sc0 sc1" \
               : "=v"(dst) : "v"(ptr) : "memory")

#define ISSUE_ROUND(buf) do { \
  LD16(buf[0],  p0, "0"); LD16(buf[1],  p0, "1024"); LD16(buf[2],  p0, "2048"); LD16(buf[3],  p0, "3072"); \
  LD16(buf[4],  p1, "0"); LD16(buf[5],  p1, "1024"); LD16(buf[6],  p1, "2048"); LD16(buf[7],  p1, "3072"); \
  LD16(buf[8],  p2, "0"); LD16(buf[9],  p2, "1024"); LD16(buf[10], p2, "2048"); LD16(buf[11], p2, "3072"); \
  LD16(buf[12], p3, "0"); LD16(buf[13], p3, "1024"); LD16(buf[14], p3, "2048"); LD16(buf[15], p3, "3072"); \
} while (0)

#define VALID16(buf, ok) do { \
  unsigned mA = umax2(umax4(buf[0]),  umax4(buf[1])); \
  unsigned mB = umax2(umax4(buf[2]),  umax4(buf[3])); \
  mA = umax2(mA, umax2(umax4(buf[4]),  umax4(buf[5]))); \
  mB = umax2(mB, umax2(umax4(buf[6]),  umax4(buf[7]))); \
  unsigned mC = umax2(umax4(buf[8]),  umax4(buf[9])); \
  unsigned mD = umax2(umax4(buf[10]), umax4(buf[11])); \
  mC = umax2(mC, umax2(umax4(buf[12]), umax4(buf[13]))); \
  mD = umax2(mD, umax2(umax4(buf[14]), umax4(buf[15]))); \
  unsigned mx = umax2(umax2(mA, mB), umax2(mC, mD)); \
  ok = !__any((int)(mx == 0xFFFFFFFFu)); \
} while (0)

#define MFMA16(buf) do { \
  _Pragma("unroll") \
  for (int s = 0; s < 16; ++s) { \
    bf16x8 af = __builtin_bit_cast(bf16x8, buf[s]); \
    acc0 = __builtin_amdgcn_mfma_f32_32x32x16_bf16(af, w0[s], acc0, 0, 0, 0); \
    acc1 = __builtin_amdgcn_mfma_f32_32x32x16_bf16(af, w1[s], acc1, 0, 0, 0); \
  } \
} while (0)

__global__ __launch_bounds__(256, 1) void lstm_rec(
    const bf16_t* __restrict__ Whh_b, const bf16_t* __restrict__ XP,
    const float* __restrict__ c0, float* __restrict__ OUT,
    bf16_t* __restrict__ HTR)
{
  const int tid = threadIdx.x;
  const int lane = tid & 63, wave = tid >> 6;
  const int kq = wave;                              // K-quarter 0..3
  const int wg = blockIdx.x;
  const int l31 = lane & 31, khi = lane >> 5;

  // --- preload W_hh fragments for BOTH n-tiles of my K-quarter ---
  const int g0row = (l31 >> 4) * 1024 + wg * 16 + (l31 & 15);
  const int g1row = (2 + (l31 >> 4)) * 1024 + wg * 16 + (l31 & 15);
  const int kqb = kq * 256 + khi * 8;               // k-base of my quarter
  bf16x8 w0[16], w1[16];
#pragma unroll
  for (int s = 0; s < 16; ++s) {
    w0[s] = *(const bf16x8*)(Whh_b + (long long)g0row * 1024 + kqb + s * 16);
    w1[s] = *(const bf16x8*)(Whh_b + (long long)g1row * 1024 + kqb + s * 16);
  }

  // A-fragment byte base: slab (kq*16+s), row l31, cols khi*8..+8
  const char* abase = (const char*)HTR + kq * 16384 + l31 * 32 + khi * 16;

  __shared__ float gLb[2][4][32][65];   // [t parity][kq][m][n_local], padded
  const int m_e = tid >> 3;
  const int jp = (tid & 7) * 2;
  float cr0 = c0[m_e * 1024 + wg * 16 + jp];
  float cr1 = c0[m_e * 1024 + wg * 16 + jp + 1];

  // prefetch xp for t=0
  float xp[4][2];
  {
    const bf16_t* xpb = XP + (long long)m_e * 4096 + wg * 16 + jp;
#pragma unroll
    for (int g = 0; g < 4; ++g) {
      bf16x2 v = *(const bf16x2*)(xpb + g * 1024);
      xp[g][0] = (float)v.x; xp[g][1] = (float)v.y;
    }
  }

  float po0 = 0.0f, po1 = 0.0f;   // deferred OUT values (step t-1)
  i32x4 a[16], b[16];             // double-buffered poll rounds

  for (int t = 0; t < 512; ++t) {
    // ---- deferred OUT store for t-1, issued BEFORE poll (hidden) ----
    if (t > 0)
      *(float2*)(OUT + ((long long)m_e * 512 + (t - 1)) * 1024 + wg * 16 + jp) =
          make_float2(po0, po1);

    const char* p0 = abase + ((long long)t << 16);
    const char* p1 = p0 + 4096;
    const char* p2 = p0 + 8192;
    const char* p3 = p0 + 12288;

    // drain last step's stale (losing) round before re-targeting a/b regs.
    // vmcnt(10) leaves exactly {publish, 8x xp, OUT} outstanding -> the
    // publish store stays fire-and-forget.
    asm volatile("s_waitcnt vmcnt(10)" ::: "memory");
    ISSUE_ROUND(a);
    ISSUE_ROUND(b);

    bool useA = true;
    for (;;) {
      asm volatile("s_waitcnt vmcnt(16)" ::: "memory");   // older round done
      __builtin_amdgcn_sched_barrier(0);
      bool ok; VALID16(a, ok);
      if (ok) { useA = true; break; }
      ISSUE_ROUND(a);
      asm volatile("s_waitcnt vmcnt(16)" ::: "memory");
      __builtin_amdgcn_sched_barrier(0);
      VALID16(b, ok);
      if (ok) { useA = false; break; }
      ISSUE_ROUND(b);
    }

    // ---- gates partial for my K-quarter, both n-tiles ----
    f32x16 acc0 = {}, acc1 = {};
    if (useA) { MFMA16(a); } else { MFMA16(b); }

    float (*gp)[65] = gLb[t & 1][kq];
#pragma unroll
    for (int r = 0; r < 16; ++r) {
      int mm = (r & 3) + 8 * (r >> 2) + 4 * khi;
      gp[mm][l31]      = acc0[r];
      gp[mm][32 + l31] = acc1[r];
    }
    __syncthreads();   // single barrier per step (gL parity-double-buffered)

    // ---- elementwise LSTM cell for (m_e, jp..jp+1), c in registers ----
    float (*ge)[32][65] = gLb[t & 1];
    float hv[2];
    {
      float ir  = ge[0][m_e][jp]      + ge[1][m_e][jp]      + ge[2][m_e][jp]      + ge[3][m_e][jp]      + xp[0][0];
      float fr  = ge[0][m_e][16 + jp] + ge[1][m_e][16 + jp] + ge[2][m_e][16 + jp] + ge[3][m_e][16 + jp] + xp[1][0];
      float gr  = ge[0][m_e][32 + jp] + ge[1][m_e][32 + jp] + ge[2][m_e][32 + jp] + ge[3][m_e][32 + jp] + xp[2][0];
      float orr = ge[0][m_e][48 + jp] + ge[1][m_e][48 + jp] + ge[2][m_e][48 + jp] + ge[3][m_e][48 + jp] + xp[3][0];
      float c = sigf(fr) * cr0 + sigf(ir) * tanhfast(gr);
      cr0 = c;
      hv[0] = sigf(orr) * tanhfast(c);
    }
    {
      int j = jp + 1;
      float ir  = ge[0][m_e][j]      + ge[1][m_e][j]      + ge[2][m_e][j]      + ge[3][m_e][j]      + xp[0][1];
      float fr  = ge[0][m_e][16 + j] + ge[1][m_e][16 + j] + ge[2][m_e][16 + j] + ge[3][m_e][16 + j] + xp[1][1];
      float gr  = ge[0][m_e][32 + j] + ge[1][m_e][32 + j] + ge[2][m_e][32 + j] + ge[3][m_e][32 + j] + xp[2][1];
      float orr = ge[0][m_e][48 + j] + ge[1][m_e][48 + j] + ge[2][m_e][48 + j] + ge[3][m_e][48 + j] + xp[3][1];
      float c = sigf(fr) * cr1 + sigf(ir) * tanhfast(gr);
      cr1 = c;
      hv[1] = sigf(orr) * tanhfast(c);
    }

    // ---- publish h: sc1 store to LLC, fire-and-forget (data IS the flag) ----
    {
      bf16x2 h2; h2.x = (bf16_t)hv[0]; h2.y = (bf16_t)hv[1];
      unsigned int u = __builtin_bit_cast(unsigned int, h2);
      unsigned int* dst = (unsigned int*)(HTR + (long long)(t + 1) * 32768 +
                                          (long long)wg * 512 + m_e * 16 + jp);
      __hip_atomic_store(dst, u, __ATOMIC_RELAXED, __HIP_MEMORY_SCOPE_AGENT);
    }
    po0 = hv[0]; po1 = hv[1];

    // ---- next-step xp prefetch ----
    if (t < 511) {
      const bf16_t* xpb = XP + ((long long)(t + 1) * 32 + m_e) * 4096 + wg * 16 + jp;
#pragma unroll
      for (int g = 0; g < 4; ++g) {
        bf16x2 v = *(const bf16x2*)(xpb + g * 1024);
        xp[g][0] = (float)v.x; xp[g][1] = (float)v.y;
      }
    }
  }
  // final OUT store (t = 511)
  *(float2*)(OUT + ((long long)m_e * 512 + 511) * 1024 + wg * 16 + jp) =
      make_float2(po0, po1);
}

// ---------------------------------------------------------------------------
extern "C" void kernel_launch(void* const* d_in, const int* in_sizes, int n_in,
                              void* d_out, int out_size, void* d_ws, size_t ws_size,
                              hipStream_t stream)
{
  const float* x   = (const float*)d_in[0];
  const float* h0  = (const float*)d_in[1];
  const float* c0  = (const float*)d_in[2];
  const float* Wih = (const float*)d_in[3];
  const float* Whh = (const float*)d_in[4];
  const float* bih = (const float*)d_in[5];
  const float* bhh = (const float*)d_in[6];
  float* out = (float*)d_out;

  char* ws = (char*)d_ws;
  bf16_t* xbf   = (bf16_t*)(ws + OFF_XBF);
  bf16_t* wihbf = (bf16_t*)(ws + OFF_WIH);
  bf16_t* whhbf = (bf16_t*)(ws + OFF_WHH);
  bf16_t* xproj = (bf16_t*)(ws + OFF_XPROJ);
  bf16_t* htr   = (bf16_t*)(ws + OFF_HTR);

  convert_pack<<<22560, 256, 0, stream>>>(x, h0, Wih, Whh, xbf, wihbf, whhbf, htr);
  xproj_gemm<<<dim3(128, 32), 256, 0, stream>>>(xbf, wihbf, bih, bhh, xproj);
  lstm_rec<<<64, 256, 0, stream>>>(whhbf, xproj, c0, out, htr);
}

// Round 10
// 1458.187 us; speedup vs baseline: 1.8936x; 1.2183x over previous
//
#include <hip/hip_runtime.h>

typedef __bf16 bf16_t;
typedef __bf16 bf16x8 __attribute__((ext_vector_type(8)));
typedef __bf16 bf16x4 __attribute__((ext_vector_type(4)));
typedef __bf16 bf16x2 __attribute__((ext_vector_type(2)));
typedef float f32x16 __attribute__((ext_vector_type(16)));
typedef int i32x4 __attribute__((ext_vector_type(4)));

// Problem dims: B=32, S=512, D=512, H=1024, 4H=4096
// ws layout (bytes)
#define SZ_XBF    (16384ull*512*2)      // x bf16, rows permuted to t*32+b
#define SZ_WIH    (4096ull*512*2)
#define SZ_WHH    (4096ull*1024*2)
#define SZ_XPROJ  (16384ull*4096*2)     // [t*32+b][4096] bf16
#define SZ_HTR    (513ull*32*1024*2)    // h trace bf16, slot 0 = h0
#define OFF_XBF   (0ull)
#define OFF_WIH   (OFF_XBF + SZ_XBF)
#define OFF_WHH   (OFF_WIH + SZ_WIH)
#define OFF_XPROJ (OFF_WHH + SZ_WHH)
#define OFF_HTR   (OFF_XPROJ + SZ_XPROJ)

// h trace layout (slab-contiguous per producer, round-4 topology — the
// verified optimum after r5-r9 all regressed):
//   HTR[t*32768 + slab*512 + b*16 + col]  encodes h_t[b][slab*16 + col]
// Each (t, slab) region is 1KB contiguous, written dword-wise by exactly one
// WG. Slots 1..512 are pre-filled with canary 0xFFFFFFFF (bf16 -NaN pair,
// impossible for real h = o*tanh(c), always finite). Consumers bulk-load
// slabs with cache-bypassing loads and retry until no canary dword remains:
// the DATA is the flag. Per-dword store atomicity makes this sound fence-free.
// Waves are K-QUARTERS: each wave loads a disjoint 16KB quarter (16 slabs),
// computing both n-tiles for it. Lean bulk poll round: issue-16 -> vmcnt(0)
// -> validate -> branch. (Fancier protocols all lost: selective retry r6,
// probe gate r7, cached+hint r8, A/B pipelined rounds r9.)

// ---------------------------------------------------------------------------
// Kernel 1: convert inputs to bf16 (x permuted), init h-trace slot 0,
//           canary-fill h-trace slots 1..512
// ---------------------------------------------------------------------------
__global__ __launch_bounds__(256) void convert_pack(
    const float* __restrict__ x, const float* __restrict__ h0,
    const float* __restrict__ Wih, const float* __restrict__ Whh,
    bf16_t* __restrict__ xbf, bf16_t* __restrict__ wihbf,
    bf16_t* __restrict__ whhbf, bf16_t* __restrict__ htr)
{
  long long v = (long long)blockIdx.x * 256 + threadIdx.x;
  if (v < 2097152LL) {                       // x: 8388608 floats, 4 per thread
    long long fi = v * 4;
    int b = (int)(fi >> 18);                 // 512*512 = 2^18
    int rem = (int)(fi & 0x3FFFF);
    int s = rem >> 9, d = rem & 511;
    float4 f = *(const float4*)(x + fi);
    bf16x4 o; o.x = (bf16_t)f.x; o.y = (bf16_t)f.y; o.z = (bf16_t)f.z; o.w = (bf16_t)f.w;
    *(bf16x4*)(xbf + ((long long)(s*32 + b)*512 + d)) = o;
  } else if (v < 2621440LL) {                // W_ih: 2097152 floats
    long long fi = (v - 2097152LL) * 4;
    float4 f = *(const float4*)(Wih + fi);
    bf16x4 o; o.x = (bf16_t)f.x; o.y = (bf16_t)f.y; o.z = (bf16_t)f.z; o.w = (bf16_t)f.w;
    *(bf16x4*)(wihbf + fi) = o;
  } else if (v < 3670016LL) {                // W_hh: 4194304 floats
    long long fi = (v - 2621440LL) * 4;
    float4 f = *(const float4*)(Whh + fi);
    bf16x4 o; o.x = (bf16_t)f.x; o.y = (bf16_t)f.y; o.z = (bf16_t)f.z; o.w = (bf16_t)f.w;
    *(bf16x4*)(whhbf + fi) = o;
  } else if (v < 3678208LL) {                // h0: 32768 floats -> htr slot 0 (slab layout)
    long long fi = (v - 3670016LL) * 4;
    int b = (int)(fi >> 10), c = (int)(fi & 1023);
    float4 f = *(const float4*)(h0 + fi);
    bf16x4 o; o.x = (bf16_t)f.x; o.y = (bf16_t)f.y; o.z = (bf16_t)f.z; o.w = (bf16_t)f.w;
    *(bf16x4*)(htr + (long long)(c >> 4) * 512 + b * 16 + (c & 15)) = o;
  } else if (v < 5775360LL) {                // canary fill slots 1..512 (16.78M elems)
    long long idx = v - 3678208LL;           // 2097152 threads * 8 elems
    *(int4*)(htr + 32768LL + idx * 8) = make_int4(-1, -1, -1, -1);
  }
}

// ---------------------------------------------------------------------------
// Kernel 2: x_proj = X(bf16, rows t*32+b) @ W_ih^T + b_ih + b_hh  -> bf16
// ---------------------------------------------------------------------------
__global__ __launch_bounds__(256) void xproj_gemm(
    const bf16_t* __restrict__ Xb, const bf16_t* __restrict__ Wb,
    const float* __restrict__ bih, const float* __restrict__ bhh,
    bf16_t* __restrict__ XP)
{
  __shared__ bf16_t As[128*64];
  __shared__ bf16_t Bs[128*64];
  const int tid = threadIdx.x;
  const int lane = tid & 63, wave = tid >> 6;
  const int mhalf = wave & 1, nhalf = wave >> 1;
  const int l31 = lane & 31, khi = lane >> 5;
  const int m0 = blockIdx.x * 128, n0 = blockIdx.y * 128;

  f32x16 acc[2][2] = {};

  for (int kb = 0; kb < 8; ++kb) {
    const int k0 = kb * 64;
    __syncthreads();
#pragma unroll
    for (int j = 0; j < 4; ++j) {
      int cid = j * 256 + tid;
      int r = cid >> 3, bs = cid & 7;
      int bb = bs ^ (r & 7);
      *(bf16x8*)(As + cid * 8) = *(const bf16x8*)(Xb + (long long)(m0 + r) * 512 + k0 + bb * 8);
      *(bf16x8*)(Bs + cid * 8) = *(const bf16x8*)(Wb + (long long)(n0 + r) * 512 + k0 + bb * 8);
    }
    __syncthreads();
#pragma unroll
    for (int ks = 0; ks < 4; ++ks) {
      int blk = ks * 2 + khi;
      bf16x8 af[2], bfr[2];
#pragma unroll
      for (int mt = 0; mt < 2; ++mt) {
        int r = mhalf * 64 + mt * 32 + l31;
        af[mt] = *(const bf16x8*)(As + (r * 8 + (blk ^ (r & 7))) * 8);
      }
#pragma unroll
      for (int nt = 0; nt < 2; ++nt) {
        int r = nhalf * 64 + nt * 32 + l31;
        bfr[nt] = *(const bf16x8*)(Bs + (r * 8 + (blk ^ (r & 7))) * 8);
      }
#pragma unroll
      for (int mt = 0; mt < 2; ++mt)
#pragma unroll
        for (int nt = 0; nt < 2; ++nt)
          acc[mt][nt] = __builtin_amdgcn_mfma_f32_32x32x16_bf16(af[mt], bfr[nt], acc[mt][nt], 0, 0, 0);
    }
  }
#pragma unroll
  for (int nt = 0; nt < 2; ++nt) {
    int ng = n0 + nhalf * 64 + nt * 32 + l31;
    float bias = bih[ng] + bhh[ng];
#pragma unroll
    for (int mt = 0; mt < 2; ++mt) {
#pragma unroll
      for (int r = 0; r < 16; ++r) {
        int row = (r & 3) + 8 * (r >> 2) + 4 * khi;
        long long mg = m0 + mhalf * 64 + mt * 32 + row;   // = t*32 + b
        XP[mg * 4096 + ng] = (bf16_t)(acc[mt][nt][r] + bias);
      }
    }
  }
}

// ---------------------------------------------------------------------------
// Kernel 3: persistent LSTM recurrence, canary-validated data-poll sync.
// 64 WGs x 256 threads; WG owns 16 h-cols (64 gate rows).
//  - wave = K-quarter: loads 16 disjoint slabs (16KB), computes BOTH n-tiles.
//  - lean bulk poll (r4-verified optimum).
//  - gL [parity][4 kq][32 m][65] double-buffered -> ONE barrier per step.
//  - c in regs; OUT deferred one step; publish fire-and-forget sc1.
//  - NEW (r10): sigf/tanhfast use v_rcp_f32 (rcpf) instead of full-precision
//    division — shaves the elementwise->publish tail; error ~1e-5 rel,
//    invisible at bf16 output precision.
// ---------------------------------------------------------------------------
__device__ __forceinline__ float sigf(float x) {
  return __builtin_amdgcn_rcpf(1.0f + __expf(-x));
}
__device__ __forceinline__ float tanhfast(float x) {
  float e = __expf(-2.0f * fabsf(x));
  float t = (1.0f - e) * __builtin_amdgcn_rcpf(1.0f + e);
  return copysignf(t, x);
}
__device__ __forceinline__ unsigned umax2(unsigned a, unsigned b) { return a > b ? a : b; }
__device__ __forceinline__ unsigned umax4(i32x4 v) {
  return umax2(umax2((unsigned)v[0], (unsigned)v[1]),
               umax2((unsigned)v[2], (unsigned)v[3]));
}

#define LD16(dst, ptr, OFF) \
  asm volatile("global_load_dwordx4 %0, %1, off offset:" OFF " sc0 sc1" \
               : "=v"(dst) : "v"(ptr) : "memory")

__global__ __launch_bounds__(256, 1) void lstm_rec(
    const bf16_t* __restrict__ Whh_b, const bf16_t* __restrict__ XP,
    const float* __restrict__ c0, float* __restrict__ OUT,
    bf16_t* __restrict__ HTR)
{
  const int tid = threadIdx.x;
  const int lane = tid & 63, wave = tid >> 6;
  const int kq = wave;                              // K-quarter 0..3
  const int wg = blockIdx.x;
  const int l31 = lane & 31, khi = lane >> 5;

  // --- preload W_hh fragments for BOTH n-tiles of my K-quarter ---
  const int g0row = (l31 >> 4) * 1024 + wg * 16 + (l31 & 15);
  const int g1row = (2 + (l31 >> 4)) * 1024 + wg * 16 + (l31 & 15);
  const int kqb = kq * 256 + khi * 8;               // k-base of my quarter
  bf16x8 w0[16], w1[16];
#pragma unroll
  for (int s = 0; s < 16; ++s) {
    w0[s] = *(const bf16x8*)(Whh_b + (long long)g0row * 1024 + kqb + s * 16);
    w1[s] = *(const bf16x8*)(Whh_b + (long long)g1row * 1024 + kqb + s * 16);
  }

  // A-fragment byte base: slab (kq*16+s), row l31, cols khi*8..+8
  //   byte = t*65536 + (kq*16+s)*1024 + l31*32 + khi*16
  const char* abase = (const char*)HTR + kq * 16384 + l31 * 32 + khi * 16;

  __shared__ float gLb[2][4][32][65];   // [t parity][kq][m][n_local], padded
  const int m_e = tid >> 3;
  const int jp = (tid & 7) * 2;
  float cr0 = c0[m_e * 1024 + wg * 16 + jp];
  float cr1 = c0[m_e * 1024 + wg * 16 + jp + 1];

  // prefetch xp for t=0
  float xp[4][2];
  {
    const bf16_t* xpb = XP + (long long)m_e * 4096 + wg * 16 + jp;
#pragma unroll
    for (int g = 0; g < 4; ++g) {
      bf16x2 v = *(const bf16x2*)(xpb + g * 1024);
      xp[g][0] = (float)v.x; xp[g][1] = (float)v.y;
    }
  }

  float po0 = 0.0f, po1 = 0.0f;   // deferred OUT values (step t-1)

  for (int t = 0; t < 512; ++t) {
    // ---- bulk-load + canary-validate the 16 slabs of my K-quarter ----
    const char* p0 = abase + ((long long)t << 16);
    const char* p1 = p0 + 4096;
    const char* p2 = p0 + 8192;
    const char* p3 = p0 + 12288;
    i32x4 a[16];
    for (;;) {
      LD16(a[0],  p0, "0"); LD16(a[1],  p0, "1024"); LD16(a[2],  p0, "2048"); LD16(a[3],  p0, "3072");
      LD16(a[4],  p1, "0"); LD16(a[5],  p1, "1024"); LD16(a[6],  p1, "2048"); LD16(a[7],  p1, "3072");
      LD16(a[8],  p2, "0"); LD16(a[9],  p2, "1024"); LD16(a[10], p2, "2048"); LD16(a[11], p2, "3072");
      LD16(a[12], p3, "0"); LD16(a[13], p3, "1024"); LD16(a[14], p3, "2048"); LD16(a[15], p3, "3072");
      asm volatile("s_waitcnt vmcnt(0)" ::: "memory");
      __builtin_amdgcn_sched_barrier(0);
      unsigned mA = 0, mB = 0, mC = 0, mD = 0;
#pragma unroll
      for (int s = 0; s < 16; s += 4) {
        mA = umax2(mA, umax4(a[s]));
        mB = umax2(mB, umax4(a[s + 1]));
        mC = umax2(mC, umax4(a[s + 2]));
        mD = umax2(mD, umax4(a[s + 3]));
      }
      unsigned mx = umax2(umax2(mA, mB), umax2(mC, mD));
      if (!__any((int)(mx == 0xFFFFFFFFu))) break;
    }

    // ---- deferred OUT store for step t-1 (ack off the critical wait) ----
    if (t > 0)
      *(float2*)(OUT + ((long long)m_e * 512 + (t - 1)) * 1024 + wg * 16 + jp) =
          make_float2(po0, po1);

    // ---- gates partial for my K-quarter, both n-tiles ----
    f32x16 acc0 = {}, acc1 = {};
#pragma unroll
    for (int s = 0; s < 16; ++s) {
      bf16x8 af = __builtin_bit_cast(bf16x8, a[s]);
      acc0 = __builtin_amdgcn_mfma_f32_32x32x16_bf16(af, w0[s], acc0, 0, 0, 0);
      acc1 = __builtin_amdgcn_mfma_f32_32x32x16_bf16(af, w1[s], acc1, 0, 0, 0);
    }

    float (*gp)[65] = gLb[t & 1][kq];
#pragma unroll
    for (int r = 0; r < 16; ++r) {
      int mm = (r & 3) + 8 * (r >> 2) + 4 * khi;
      gp[mm][l31]      = acc0[r];
      gp[mm][32 + l31] = acc1[r];
    }
    __syncthreads();   // single barrier per step (gL parity-double-buffered)

    // ---- elementwise LSTM cell for (m_e, jp..jp+1), c in registers ----
    float (*ge)[32][65] = gLb[t & 1];
    float hv[2];
    {
      float ir  = ge[0][m_e][jp]      + ge[1][m_e][jp]      + ge[2][m_e][jp]      + ge[3][m_e][jp]      + xp[0][0];
      float fr  = ge[0][m_e][16 + jp] + ge[1][m_e][16 + jp] + ge[2][m_e][16 + jp] + ge[3][m_e][16 + jp] + xp[1][0];
      float gr  = ge[0][m_e][32 + jp] + ge[1][m_e][32 + jp] + ge[2][m_e][32 + jp] + ge[3][m_e][32 + jp] + xp[2][0];
      float orr = ge[0][m_e][48 + jp] + ge[1][m_e][48 + jp] + ge[2][m_e][48 + jp] + ge[3][m_e][48 + jp] + xp[3][0];
      float c = sigf(fr) * cr0 + sigf(ir) * tanhfast(gr);
      cr0 = c;
      hv[0] = sigf(orr) * tanhfast(c);
    }
    {
      int j = jp + 1;
      float ir  = ge[0][m_e][j]      + ge[1][m_e][j]      + ge[2][m_e][j]      + ge[3][m_e][j]      + xp[0][1];
      float fr  = ge[0][m_e][16 + j] + ge[1][m_e][16 + j] + ge[2][m_e][16 + j] + ge[3][m_e][16 + j] + xp[1][1];
      float gr  = ge[0][m_e][32 + j] + ge[1][m_e][32 + j] + ge[2][m_e][32 + j] + ge[3][m_e][32 + j] + xp[2][1];
      float orr = ge[0][m_e][48 + j] + ge[1][m_e][48 + j] + ge[2][m_e][48 + j] + ge[3][m_e][48 + j] + xp[3][1];
      float c = sigf(fr) * cr1 + sigf(ir) * tanhfast(gr);
      cr1 = c;
      hv[1] = sigf(orr) * tanhfast(c);
    }

    // ---- publish h: sc1 store to LLC, fire-and-forget (data IS the flag) ----
    {
      bf16x2 h2; h2.x = (bf16_t)hv[0]; h2.y = (bf16_t)hv[1];
      unsigned int u = __builtin_bit_cast(unsigned int, h2);
      unsigned int* dst = (unsigned int*)(HTR + (long long)(t + 1) * 32768 +
                                          (long long)wg * 512 + m_e * 16 + jp);
      __hip_atomic_store(dst, u, __ATOMIC_RELAXED, __HIP_MEMORY_SCOPE_AGENT);
    }
    po0 = hv[0]; po1 = hv[1];

    // ---- next-step xp prefetch ----
    if (t < 511) {
      const bf16_t* xpb = XP + ((long long)(t + 1) * 32 + m_e) * 4096 + wg * 16 + jp;
#pragma unroll
      for (int g = 0; g < 4; ++g) {
        bf16x2 v = *(const bf16x2*)(xpb + g * 1024);
        xp[g][0] = (float)v.x; xp[g][1] = (float)v.y;
      }
    }
  }
  // final OUT store (t = 511)
  *(float2*)(OUT + ((long long)m_e * 512 + 511) * 1024 + wg * 16 + jp) =
      make_float2(po0, po1);
}

// ---------------------------------------------------------------------------
extern "C" void kernel_launch(void* const* d_in, const int* in_sizes, int n_in,
                              void* d_out, int out_size, void* d_ws, size_t ws_size,
                              hipStream_t stream)
{
  const float* x   = (const float*)d_in[0];
  const float* h0  = (const float*)d_in[1];
  const float* c0  = (const float*)d_in[2];
  const float* Wih = (const float*)d_in[3];
  const float* Whh = (const float*)d_in[4];
  const float* bih = (const float*)d_in[5];
  const float* bhh = (const float*)d_in[6];
  float* out = (float*)d_out;

  char* ws = (char*)d_ws;
  bf16_t* xbf   = (bf16_t*)(ws + OFF_XBF);
  bf16_t* wihbf = (bf16_t*)(ws + OFF_WIH);
  bf16_t* whhbf = (bf16_t*)(ws + OFF_WHH);
  bf16_t* xproj = (bf16_t*)(ws + OFF_XPROJ);
  bf16_t* htr   = (bf16_t*)(ws + OFF_HTR);

  convert_pack<<<22560, 256, 0, stream>>>(x, h0, Wih, Whh, xbf, wihbf, whhbf, htr);
  xproj_gemm<<<dim3(128, 32), 256, 0, stream>>>(xbf, wihbf, bih, bhh, xproj);
  lstm_rec<<<64, 256, 0, stream>>>(whhbf, xproj, c0, out, htr);
}